// Round 1
// baseline (859.709 us; speedup 1.0000x reference)
//
#include <hip/hip_runtime.h>

#define ZD 32
#define YD 16
#define XD 64
#define NA 4
#define TH 64
#define HH 32
#define IN1 (ZD + XD + YD)   // 112
#define IN2 (ZD + YD)        // 48
#define SUP 2
#define INNER 2

// k is always a compile-time constant after full unroll -> folds to a single
// register reference (no runtime-indexed local arrays -> no scratch).
#define INP(k)  ((k) < ZD ? z[(k)] : ((k) < ZD + XD ? x[(k) - ZD] : y[(k) - ZD - XD]))
#define HINP(k) ((k) < ZD ? z[(k)] : y[(k) - ZD])

__global__ __launch_bounds__(256, 2) void trm_fwd(
    const float* __restrict__ state,
    const int*   __restrict__ pact,
    const float* __restrict__ z0,
    const float* __restrict__ Wt1, const float* __restrict__ bt1,
    const float* __restrict__ Wt2, const float* __restrict__ bt2,
    const float* __restrict__ Wh1, const float* __restrict__ bh1,
    const float* __restrict__ Wh2, const float* __restrict__ bh2,
    const float* __restrict__ emb,
    float* __restrict__ out, int B)
{
    const int b = blockIdx.x * 256 + threadIdx.x;
    if (b >= B) return;

    float x[XD], y[YD], z[ZD];

    // x: 16 coalesced-ish dwordx4 loads (each thread reads its contiguous row)
    {
        const float4* sp = reinterpret_cast<const float4*>(state) + (size_t)b * (XD / 4);
        #pragma unroll
        for (int i = 0; i < XD / 4; ++i) {
            const float4 v = sp[i];
            x[4*i+0] = v.x; x[4*i+1] = v.y; x[4*i+2] = v.z; x[4*i+3] = v.w;
        }
    }
    // y = emb[prev_action]
    {
        const int a = pact[b];
        #pragma unroll
        for (int i = 0; i < YD / 4; ++i) {
            const float4 v = *reinterpret_cast<const float4*>(emb + a * YD + 4*i);
            y[4*i+0] = v.x; y[4*i+1] = v.y; y[4*i+2] = v.z; y[4*i+3] = v.w;
        }
    }
    #pragma unroll
    for (int i = 0; i < ZD; ++i) z[i] = z0[i];

    float lg[NA];

    #pragma unroll 1
    for (int s = 0; s < SUP; ++s) {
        // ---- INNER_STEPS x tiny: z = Wt2 @ relu(Wt1 @ [z,x,y] + bt1) + bt2
        #pragma unroll 1
        for (int it = 0; it < INNER; ++it) {
            float zn[ZD];
            #pragma unroll
            for (int i = 0; i < ZD; ++i) zn[i] = bt2[i];

            #pragma unroll 1
            for (int j0 = 0; j0 < TH; j0 += 4) {   // 4 output rows at a time (ILP)
                const float* w0 = Wt1 + (j0+0)*IN1;
                const float* w1 = Wt1 + (j0+1)*IN1;
                const float* w2 = Wt1 + (j0+2)*IN1;
                const float* w3 = Wt1 + (j0+3)*IN1;
                float a0 = bt1[j0+0], a1 = bt1[j0+1], a2 = bt1[j0+2], a3 = bt1[j0+3];
                #pragma unroll
                for (int q = 0; q < IN1/4; ++q) {
                    const float4 v0 = *reinterpret_cast<const float4*>(w0 + 4*q);
                    const float4 v1 = *reinterpret_cast<const float4*>(w1 + 4*q);
                    const float4 v2 = *reinterpret_cast<const float4*>(w2 + 4*q);
                    const float4 v3 = *reinterpret_cast<const float4*>(w3 + 4*q);
                    const float i0 = INP(4*q+0);
                    const float i1 = INP(4*q+1);
                    const float i2 = INP(4*q+2);
                    const float i3 = INP(4*q+3);
                    a0 = fmaf(v0.w, i3, fmaf(v0.z, i2, fmaf(v0.y, i1, fmaf(v0.x, i0, a0))));
                    a1 = fmaf(v1.w, i3, fmaf(v1.z, i2, fmaf(v1.y, i1, fmaf(v1.x, i0, a1))));
                    a2 = fmaf(v2.w, i3, fmaf(v2.z, i2, fmaf(v2.y, i1, fmaf(v2.x, i0, a2))));
                    a3 = fmaf(v3.w, i3, fmaf(v3.z, i2, fmaf(v3.y, i1, fmaf(v3.x, i0, a3))));
                }
                const float h0 = fmaxf(a0, 0.f), h1 = fmaxf(a1, 0.f);
                const float h2 = fmaxf(a2, 0.f), h3 = fmaxf(a3, 0.f);
                // zn += Wt2[:, j0:j0+4] @ h   (columns j0..j0+3 are contiguous)
                #pragma unroll
                for (int i = 0; i < ZD; ++i) {
                    const float4 wv = *reinterpret_cast<const float4*>(Wt2 + i*TH + j0);
                    zn[i] = fmaf(wv.w, h3, fmaf(wv.z, h2, fmaf(wv.y, h1, fmaf(wv.x, h0, zn[i]))));
                }
            }
            #pragma unroll
            for (int i = 0; i < ZD; ++i) z[i] = zn[i];
        }

        // ---- head: logits = Wh2 @ relu(Wh1 @ [z,y] + bh1) + bh2
        lg[0] = bh2[0]; lg[1] = bh2[1]; lg[2] = bh2[2]; lg[3] = bh2[3];
        #pragma unroll 1
        for (int j0 = 0; j0 < HH; j0 += 4) {
            const float* w0 = Wh1 + (j0+0)*IN2;
            const float* w1 = Wh1 + (j0+1)*IN2;
            const float* w2 = Wh1 + (j0+2)*IN2;
            const float* w3 = Wh1 + (j0+3)*IN2;
            float a0 = bh1[j0+0], a1 = bh1[j0+1], a2 = bh1[j0+2], a3 = bh1[j0+3];
            #pragma unroll
            for (int q = 0; q < IN2/4; ++q) {
                const float4 v0 = *reinterpret_cast<const float4*>(w0 + 4*q);
                const float4 v1 = *reinterpret_cast<const float4*>(w1 + 4*q);
                const float4 v2 = *reinterpret_cast<const float4*>(w2 + 4*q);
                const float4 v3 = *reinterpret_cast<const float4*>(w3 + 4*q);
                const float i0 = HINP(4*q+0);
                const float i1 = HINP(4*q+1);
                const float i2 = HINP(4*q+2);
                const float i3 = HINP(4*q+3);
                a0 = fmaf(v0.w, i3, fmaf(v0.z, i2, fmaf(v0.y, i1, fmaf(v0.x, i0, a0))));
                a1 = fmaf(v1.w, i3, fmaf(v1.z, i2, fmaf(v1.y, i1, fmaf(v1.x, i0, a1))));
                a2 = fmaf(v2.w, i3, fmaf(v2.z, i2, fmaf(v2.y, i1, fmaf(v2.x, i0, a2))));
                a3 = fmaf(v3.w, i3, fmaf(v3.z, i2, fmaf(v3.y, i1, fmaf(v3.x, i0, a3))));
            }
            const float h0 = fmaxf(a0, 0.f), h1 = fmaxf(a1, 0.f);
            const float h2 = fmaxf(a2, 0.f), h3 = fmaxf(a3, 0.f);
            #pragma unroll
            for (int p = 0; p < NA; ++p) {
                const float4 wv = *reinterpret_cast<const float4*>(Wh2 + p*HH + j0);
                lg[p] = fmaf(wv.w, h3, fmaf(wv.z, h2, fmaf(wv.y, h1, fmaf(wv.x, h0, lg[p]))));
            }
        }

        // ---- softmax + y update (dead after the last sup step -> skip)
        if (s + 1 < SUP) {
            const float m  = fmaxf(fmaxf(lg[0], lg[1]), fmaxf(lg[2], lg[3]));
            const float e0 = __expf(lg[0]-m), e1 = __expf(lg[1]-m);
            const float e2 = __expf(lg[2]-m), e3 = __expf(lg[3]-m);
            const float inv = 1.0f / (e0+e1+e2+e3);
            const float p0 = e0*inv, p1 = e1*inv, p2 = e2*inv, p3 = e3*inv;
            #pragma unroll
            for (int i = 0; i < YD; ++i) {
                y[i] = fmaf(p3, emb[3*YD+i],
                       fmaf(p2, emb[2*YD+i],
                       fmaf(p1, emb[1*YD+i], p0 * emb[0*YD+i])));
            }
        }
    }

    float4 o; o.x = lg[0]; o.y = lg[1]; o.z = lg[2]; o.w = lg[3];
    reinterpret_cast<float4*>(out)[b] = o;
}

extern "C" void kernel_launch(void* const* d_in, const int* in_sizes, int n_in,
                              void* d_out, int out_size, void* d_ws, size_t ws_size,
                              hipStream_t stream) {
    const float* state = (const float*)d_in[0];
    const int*   pact  = (const int*)  d_in[1];
    const float* z0    = (const float*)d_in[2];
    const float* Wt1   = (const float*)d_in[3];
    const float* bt1   = (const float*)d_in[4];
    const float* Wt2   = (const float*)d_in[5];
    const float* bt2   = (const float*)d_in[6];
    const float* Wh1   = (const float*)d_in[7];
    const float* bh1   = (const float*)d_in[8];
    const float* Wh2   = (const float*)d_in[9];
    const float* bh2   = (const float*)d_in[10];
    const float* emb   = (const float*)d_in[11];
    float* out = (float*)d_out;

    const int B = in_sizes[0] / XD;          // 524288
    const int grid = (B + 255) / 256;        // 2048
    trm_fwd<<<grid, 256, 0, stream>>>(state, pact, z0, Wt1, bt1, Wt2, bt2,
                                      Wh1, bh1, Wh2, bh2, emb, out, B);
}

// Round 2
// 73.581 us; speedup vs baseline: 11.6839x; 11.6839x over previous
//
#include <hip/hip_runtime.h>
#include <hip/hip_bf16.h>

typedef __attribute__((ext_vector_type(8))) short bf16x8;
typedef __attribute__((ext_vector_type(4))) float f32x4;

#define MFMA16(A,B,C) __builtin_amdgcn_mfma_f32_16x16x32_bf16((A),(B),(C),0,0,0)

static __device__ __forceinline__ f32x4 ld4(const float* p){
  return *(const f32x4*)p;
}
static __device__ __forceinline__ unsigned pk2(float a, float b){
  __hip_bfloat162 h = __float22bfloat162_rn(float2{a,b});
  unsigned u; __builtin_memcpy(&u, &h, 4); return u;
}
static __device__ __forceinline__ bf16x8 mk8(float a,float b,float c,float d,
                                             float e,float f,float g,float h){
  union { bf16x8 v; unsigned u[4]; } r;
  r.u[0]=pk2(a,b); r.u[1]=pk2(c,d); r.u[2]=pk2(e,f); r.u[3]=pk2(g,h);
  return r.v;
}
static __device__ __forceinline__ bf16x8 mk8v(f32x4 a, f32x4 b){
  return mk8(a[0],a[1],a[2],a[3],b[0],b[1],b[2],b[3]);
}
static __device__ __forceinline__ bf16x8 mk8r(f32x4 a, f32x4 b){ // relu + pack
  return mk8(fmaxf(a[0],0.f),fmaxf(a[1],0.f),fmaxf(a[2],0.f),fmaxf(a[3],0.f),
             fmaxf(b[0],0.f),fmaxf(b[1],0.f),fmaxf(b[2],0.f),fmaxf(b[3],0.f));
}
static __device__ __forceinline__ bf16x8 zero8(){
  bf16x8 v;
  #pragma unroll
  for(int i=0;i<8;++i) v[i]=0;
  return v;
}

// Layout conventions (verified C/D layout, learn_hip m89):
//   A-frag: row = lane&15, k = (lane>>4)*8 + j          (weights)
//   B-frag: col = lane&15, k = (lane>>4)*8 + j          (batch activations)
//   C/D   : col = lane&15, row = (lane>>4)*4 + reg
// Scramble sigma: feature h = Mt*16 + hi*4 + reg  <->  k-slot Kt*32 + hi*8 + jj
//   with Kt = Mt>>1, jj = (Mt&1)*4 + reg. Applied to Wt2/Wh2 K-cols, z-cols
//   of Wt1/Wh1, and z0, so layer-out -> layer-in needs no cross-lane moves.
__global__ __launch_bounds__(256, 2) void trm_mfma(
    const float* __restrict__ state, const int* __restrict__ pact,
    const float* __restrict__ z0,
    const float* __restrict__ Wt1, const float* __restrict__ bt1,
    const float* __restrict__ Wt2, const float* __restrict__ bt2,
    const float* __restrict__ Wh1, const float* __restrict__ bh1,
    const float* __restrict__ Wh2, const float* __restrict__ bh2,
    const float* __restrict__ emb, float* __restrict__ out,
    int ntiles, int wstride)
{
  const int lane = threadIdx.x & 63;
  const int wid  = blockIdx.x * (blockDim.x >> 6) + (threadIdx.x >> 6);
  const int r16  = lane & 15;   // A-row / B-col / C-col
  const int hi   = lane >> 4;   // k-group (inputs) / row-group (C)
  const int he   = hi & 1;      // clamped group for 16-wide (y) loads

  // ---------------- weight / bias / z0 fragments (persistent) --------------
  bf16x8 wt1f[4][4];
  #pragma unroll
  for (int m=0;m<4;++m){
    const float* w = Wt1 + (m*16 + r16)*112;
    wt1f[m][0] = mk8v(ld4(w + hi*4),       ld4(w + 16 + hi*4));   // z (scrambled)
    wt1f[m][1] = mk8v(ld4(w + 32 + hi*8),  ld4(w + 36 + hi*8));   // x[0:32]
    wt1f[m][2] = mk8v(ld4(w + 64 + hi*8),  ld4(w + 68 + hi*8));   // x[32:64]
    bf16x8 yfrag = mk8v(ld4(w + 96 + he*8), ld4(w + 100 + he*8)); // y(16)+pad
    if (hi >= 2) yfrag = zero8();
    wt1f[m][3] = yfrag;
  }
  bf16x8 wt2f[2][2];
  #pragma unroll
  for (int m=0;m<2;++m){
    const float* w = Wt2 + (m*16 + r16)*64;
    wt2f[m][0] = mk8v(ld4(w + hi*4),      ld4(w + 16 + hi*4));    // h-cols scrambled
    wt2f[m][1] = mk8v(ld4(w + 32 + hi*4), ld4(w + 48 + hi*4));
  }
  bf16x8 wh1f[2][2];
  #pragma unroll
  for (int m=0;m<2;++m){
    const float* w = Wh1 + (m*16 + r16)*48;
    wh1f[m][0] = mk8v(ld4(w + hi*4), ld4(w + 16 + hi*4));         // z (scrambled)
    bf16x8 yfrag = mk8v(ld4(w + 32 + he*8), ld4(w + 36 + he*8));  // y(16)+pad
    if (hi >= 2) yfrag = zero8();
    wh1f[m][1] = yfrag;
  }
  bf16x8 wh2f;
  {
    const float* w = Wh2 + ((r16 < 4) ? r16 : 0)*32;
    bf16x8 t = mk8v(ld4(w + hi*4), ld4(w + 16 + hi*4));           // h-cols scrambled
    if (r16 >= 4) t = zero8();                                    // pad rows 4..15
    wh2f = t;
  }
  f32x4 bt1r[4], bt2r[2], bh1r[2], bh2r;
  #pragma unroll
  for (int m=0;m<4;++m) bt1r[m] = ld4(bt1 + m*16 + hi*4);
  #pragma unroll
  for (int m=0;m<2;++m) bt2r[m] = ld4(bt2 + m*16 + hi*4);
  #pragma unroll
  for (int m=0;m<2;++m) bh1r[m] = ld4(bh1 + m*16 + hi*4);
  {
    f32x4 t = ld4(bh2);
    float msk = (hi == 0) ? 1.f : 0.f;
    bh2r = t * msk;
  }
  const bf16x8 z0f = mk8v(ld4(z0 + hi*4), ld4(z0 + 16 + hi*4));   // scrambled

  // ---------------- batch-tile loop (16 cols per wave-iteration) -----------
  #pragma unroll 1
  for (int t = wid; t < ntiles; t += wstride){
    const int col = t*16 + r16;
    const float* xr = state + (size_t)col*64;
    bf16x8 xf0 = mk8v(ld4(xr + hi*8),      ld4(xr + hi*8 + 4));
    bf16x8 xf1 = mk8v(ld4(xr + 32 + hi*8), ld4(xr + 36 + hi*8));
    bf16x8 yf;
    {
      const int act = pact[col];
      const float* er = emb + act*16 + he*8;
      yf = mk8v(ld4(er), ld4(er + 4));
      if (hi >= 2) yf = zero8();
    }
    bf16x8 zf = z0f;
    f32x4 lgv;

    #pragma unroll
    for (int s=0;s<2;++s){
      #pragma unroll
      for (int it=0; it<2; ++it){
        f32x4 c0=bt1r[0], c1=bt1r[1], c2=bt1r[2], c3=bt1r[3];
        c0=MFMA16(wt1f[0][0], zf,  c0); c1=MFMA16(wt1f[1][0], zf,  c1);
        c2=MFMA16(wt1f[2][0], zf,  c2); c3=MFMA16(wt1f[3][0], zf,  c3);
        c0=MFMA16(wt1f[0][1], xf0, c0); c1=MFMA16(wt1f[1][1], xf0, c1);
        c2=MFMA16(wt1f[2][1], xf0, c2); c3=MFMA16(wt1f[3][1], xf0, c3);
        c0=MFMA16(wt1f[0][2], xf1, c0); c1=MFMA16(wt1f[1][2], xf1, c1);
        c2=MFMA16(wt1f[2][2], xf1, c2); c3=MFMA16(wt1f[3][2], xf1, c3);
        c0=MFMA16(wt1f[0][3], yf,  c0); c1=MFMA16(wt1f[1][3], yf,  c1);
        c2=MFMA16(wt1f[2][3], yf,  c2); c3=MFMA16(wt1f[3][3], yf,  c3);
        bf16x8 h0 = mk8r(c0, c1);             // K-tile 0 of hidden (scrambled)
        bf16x8 h1 = mk8r(c2, c3);             // K-tile 1
        f32x4 d0 = bt2r[0], d1 = bt2r[1];
        d0=MFMA16(wt2f[0][0], h0, d0); d1=MFMA16(wt2f[1][0], h0, d1);
        d0=MFMA16(wt2f[0][1], h1, d0); d1=MFMA16(wt2f[1][1], h1, d1);
        zf = mk8v(d0, d1);                    // z (scrambled), in-lane
      }
      f32x4 g0 = bh1r[0], g1 = bh1r[1];
      g0=MFMA16(wh1f[0][0], zf, g0); g1=MFMA16(wh1f[1][0], zf, g1);
      g0=MFMA16(wh1f[0][1], yf, g0); g1=MFMA16(wh1f[1][1], yf, g1);
      bf16x8 hh = mk8r(g0, g1);
      f32x4 cl = bh2r;
      cl = MFMA16(wh2f, hh, cl);              // logits: hi==0 lanes, regs 0..3
      lgv = cl;
      if (s == 0){
        float l0 = __shfl(cl[0], r16), l1 = __shfl(cl[1], r16);
        float l2 = __shfl(cl[2], r16), l3 = __shfl(cl[3], r16);
        float mx = fmaxf(fmaxf(l0,l1), fmaxf(l2,l3));
        float p0=__expf(l0-mx), p1=__expf(l1-mx);
        float p2=__expf(l2-mx), p3=__expf(l3-mx);
        float inv = 1.f/(p0+p1+p2+p3);
        p0*=inv; p1*=inv; p2*=inv; p3*=inv;
        const float* eb = emb + he*8;
        f32x4 ya = ld4(eb)*p0      + ld4(eb+16)*p1 +
                   ld4(eb+32)*p2   + ld4(eb+48)*p3;
        f32x4 yb = ld4(eb+4)*p0    + ld4(eb+20)*p1 +
                   ld4(eb+36)*p2   + ld4(eb+52)*p3;
        yf = mk8v(ya, yb);
        if (hi >= 2) yf = zero8();
      }
    }
    if (hi == 0) *(f32x4*)(out + (size_t)col*4) = lgv;
  }
}

extern "C" void kernel_launch(void* const* d_in, const int* in_sizes, int n_in,
                              void* d_out, int out_size, void* d_ws, size_t ws_size,
                              hipStream_t stream) {
  const float* state = (const float*)d_in[0];
  const int*   pact  = (const int*)  d_in[1];
  const float* z0    = (const float*)d_in[2];
  const float* Wt1   = (const float*)d_in[3];
  const float* bt1   = (const float*)d_in[4];
  const float* Wt2   = (const float*)d_in[5];
  const float* bt2   = (const float*)d_in[6];
  const float* Wh1   = (const float*)d_in[7];
  const float* bh1   = (const float*)d_in[8];
  const float* Wh2   = (const float*)d_in[9];
  const float* bh2   = (const float*)d_in[10];
  const float* emb   = (const float*)d_in[11];
  float* out = (float*)d_out;

  const int B = in_sizes[0] / 64;         // 524288
  const int ntiles = B / 16;              // 32768
  const int blocks = 1024;                // 4 waves/block -> 4096 waves
  const int wstride = blocks * 4;
  trm_mfma<<<blocks, 256, 0, stream>>>(state, pact, z0, Wt1, bt1, Wt2, bt2,
                                       Wh1, bh1, Wh2, bh2, emb, out,
                                       ntiles, wstride);
}

// Round 3
// 73.163 us; speedup vs baseline: 11.7505x; 1.0057x over previous
//
#include <hip/hip_runtime.h>
#include <hip/hip_bf16.h>

typedef __attribute__((ext_vector_type(8))) short bf16x8;
typedef __attribute__((ext_vector_type(4))) float f32x4;

#define MFMA16(A,B,C) __builtin_amdgcn_mfma_f32_16x16x32_bf16((A),(B),(C),0,0,0)

static __device__ __forceinline__ f32x4 ld4(const float* p){
  return *(const f32x4*)p;
}
// Single-instruction packed f32->bf16 (RTNE). dst.lo = bf16(a), dst.hi = bf16(b).
static __device__ __forceinline__ unsigned pk2(float a, float b){
  unsigned r;
  asm("v_cvt_pk_bf16_f32 %0, %1, %2" : "=v"(r) : "v"(a), "v"(b));
  return r;
}
static __device__ __forceinline__ bf16x8 mk8(float a,float b,float c,float d,
                                             float e,float f,float g,float h){
  union { bf16x8 v; unsigned u[4]; } r;
  r.u[0]=pk2(a,b); r.u[1]=pk2(c,d); r.u[2]=pk2(e,f); r.u[3]=pk2(g,h);
  return r.v;
}
static __device__ __forceinline__ bf16x8 mk8v(f32x4 a, f32x4 b){
  return mk8(a[0],a[1],a[2],a[3],b[0],b[1],b[2],b[3]);
}
static __device__ __forceinline__ bf16x8 mk8r(f32x4 a, f32x4 b){ // relu + pack
  return mk8(fmaxf(a[0],0.f),fmaxf(a[1],0.f),fmaxf(a[2],0.f),fmaxf(a[3],0.f),
             fmaxf(b[0],0.f),fmaxf(b[1],0.f),fmaxf(b[2],0.f),fmaxf(b[3],0.f));
}
static __device__ __forceinline__ bf16x8 zero8(){
  bf16x8 v;
  #pragma unroll
  for(int i=0;i<8;++i) v[i]=0;
  return v;
}

// Layout conventions (verified C/D layout, learn_hip m89):
//   A-frag: row = lane&15, k = (lane>>4)*8 + j          (weights)
//   B-frag: col = lane&15, k = (lane>>4)*8 + j          (batch activations)
//   C/D   : col = lane&15, row = (lane>>4)*4 + reg
// Scramble sigma: feature h = Mt*16 + hi*4 + reg  <->  k-slot Kt*32 + hi*8 + jj
//   with Kt = Mt>>1, jj = (Mt&1)*4 + reg. Applied to Wt2/Wh2 K-cols, z-cols
//   of Wt1/Wh1, and z0, so layer-out -> layer-in needs no cross-lane moves.
//
// __launch_bounds__(256,1): ~190 persistent VGPRs (weights+biases as frags)
// MUST stay resident; the (256,2) cap of 128 forced per-tile rematerialization
// of weight fragments (R2 post-mortem: 5x VALU overcount, VGPR_Count==128).
__global__ __launch_bounds__(256, 1) void trm_mfma(
    const float* __restrict__ state, const int* __restrict__ pact,
    const float* __restrict__ z0,
    const float* __restrict__ Wt1, const float* __restrict__ bt1,
    const float* __restrict__ Wt2, const float* __restrict__ bt2,
    const float* __restrict__ Wh1, const float* __restrict__ bh1,
    const float* __restrict__ Wh2, const float* __restrict__ bh2,
    const float* __restrict__ emb, float* __restrict__ out,
    int ntiles, int wstride)
{
  const int lane = threadIdx.x & 63;
  const int wid  = blockIdx.x * (blockDim.x >> 6) + (threadIdx.x >> 6);
  const int r16  = lane & 15;   // A-row / B-col / C-col
  const int hi   = lane >> 4;   // k-group (inputs) / row-group (C)
  const int he   = hi & 1;      // clamped group for 16-wide (y) loads

  // ---------------- weight / bias / z0 fragments (persistent) --------------
  bf16x8 wt1f[4][4];
  #pragma unroll
  for (int m=0;m<4;++m){
    const float* w = Wt1 + (m*16 + r16)*112;
    wt1f[m][0] = mk8v(ld4(w + hi*4),       ld4(w + 16 + hi*4));   // z (scrambled)
    wt1f[m][1] = mk8v(ld4(w + 32 + hi*8),  ld4(w + 36 + hi*8));   // x[0:32]
    wt1f[m][2] = mk8v(ld4(w + 64 + hi*8),  ld4(w + 68 + hi*8));   // x[32:64]
    bf16x8 yfrag = mk8v(ld4(w + 96 + he*8), ld4(w + 100 + he*8)); // y(16)+pad
    if (hi >= 2) yfrag = zero8();
    wt1f[m][3] = yfrag;
  }
  bf16x8 wt2f[2][2];
  #pragma unroll
  for (int m=0;m<2;++m){
    const float* w = Wt2 + (m*16 + r16)*64;
    wt2f[m][0] = mk8v(ld4(w + hi*4),      ld4(w + 16 + hi*4));    // h-cols scrambled
    wt2f[m][1] = mk8v(ld4(w + 32 + hi*4), ld4(w + 48 + hi*4));
  }
  bf16x8 wh1f[2][2];
  #pragma unroll
  for (int m=0;m<2;++m){
    const float* w = Wh1 + (m*16 + r16)*48;
    wh1f[m][0] = mk8v(ld4(w + hi*4), ld4(w + 16 + hi*4));         // z (scrambled)
    bf16x8 yfrag = mk8v(ld4(w + 32 + he*8), ld4(w + 36 + he*8));  // y(16)+pad
    if (hi >= 2) yfrag = zero8();
    wh1f[m][1] = yfrag;
  }
  bf16x8 wh2f;
  {
    const float* w = Wh2 + ((r16 < 4) ? r16 : 0)*32;
    bf16x8 t = mk8v(ld4(w + hi*4), ld4(w + 16 + hi*4));           // h-cols scrambled
    if (r16 >= 4) t = zero8();                                    // pad rows 4..15
    wh2f = t;
  }
  f32x4 bt1r[4], bt2r[2], bh1r[2], bh2r;
  #pragma unroll
  for (int m=0;m<4;++m) bt1r[m] = ld4(bt1 + m*16 + hi*4);
  #pragma unroll
  for (int m=0;m<2;++m) bt2r[m] = ld4(bt2 + m*16 + hi*4);
  #pragma unroll
  for (int m=0;m<2;++m) bh1r[m] = ld4(bh1 + m*16 + hi*4);
  {
    f32x4 t = ld4(bh2);
    float msk = (hi == 0) ? 1.f : 0.f;
    bh2r = t * msk;
  }
  const bf16x8 z0f = mk8v(ld4(z0 + hi*4), ld4(z0 + 16 + hi*4));   // scrambled

  // ---------------- batch-tile loop (16 cols per wave-iteration) -----------
  #pragma unroll 1
  for (int t = wid; t < ntiles; t += wstride){
    const int col = t*16 + r16;
    const float* xr = state + (size_t)col*64;
    bf16x8 xf0 = mk8v(ld4(xr + hi*8),      ld4(xr + hi*8 + 4));
    bf16x8 xf1 = mk8v(ld4(xr + 32 + hi*8), ld4(xr + 36 + hi*8));
    bf16x8 yf;
    {
      const int act = pact[col];
      const float* er = emb + act*16 + he*8;
      yf = mk8v(ld4(er), ld4(er + 4));
      if (hi >= 2) yf = zero8();
    }
    bf16x8 zf = z0f;
    f32x4 lgv;

    #pragma unroll
    for (int s=0;s<2;++s){
      #pragma unroll
      for (int it=0; it<2; ++it){
        f32x4 c0=bt1r[0], c1=bt1r[1], c2=bt1r[2], c3=bt1r[3];
        c0=MFMA16(wt1f[0][0], zf,  c0); c1=MFMA16(wt1f[1][0], zf,  c1);
        c2=MFMA16(wt1f[2][0], zf,  c2); c3=MFMA16(wt1f[3][0], zf,  c3);
        c0=MFMA16(wt1f[0][1], xf0, c0); c1=MFMA16(wt1f[1][1], xf0, c1);
        c2=MFMA16(wt1f[2][1], xf0, c2); c3=MFMA16(wt1f[3][1], xf0, c3);
        c0=MFMA16(wt1f[0][2], xf1, c0); c1=MFMA16(wt1f[1][2], xf1, c1);
        c2=MFMA16(wt1f[2][2], xf1, c2); c3=MFMA16(wt1f[3][2], xf1, c3);
        c0=MFMA16(wt1f[0][3], yf,  c0); c1=MFMA16(wt1f[1][3], yf,  c1);
        c2=MFMA16(wt1f[2][3], yf,  c2); c3=MFMA16(wt1f[3][3], yf,  c3);
        bf16x8 h0 = mk8r(c0, c1);             // K-tile 0 of hidden (scrambled)
        bf16x8 h1 = mk8r(c2, c3);             // K-tile 1
        f32x4 d0 = bt2r[0], d1 = bt2r[1];
        d0=MFMA16(wt2f[0][0], h0, d0); d1=MFMA16(wt2f[1][0], h0, d1);
        d0=MFMA16(wt2f[0][1], h1, d0); d1=MFMA16(wt2f[1][1], h1, d1);
        zf = mk8v(d0, d1);                    // z (scrambled), in-lane
      }
      f32x4 g0 = bh1r[0], g1 = bh1r[1];
      g0=MFMA16(wh1f[0][0], zf, g0); g1=MFMA16(wh1f[1][0], zf, g1);
      g0=MFMA16(wh1f[0][1], yf, g0); g1=MFMA16(wh1f[1][1], yf, g1);
      bf16x8 hh = mk8r(g0, g1);
      f32x4 cl = bh2r;
      cl = MFMA16(wh2f, hh, cl);              // logits: hi==0 lanes, regs 0..3
      lgv = cl;
      if (s == 0){
        float l0 = __shfl(cl[0], r16), l1 = __shfl(cl[1], r16);
        float l2 = __shfl(cl[2], r16), l3 = __shfl(cl[3], r16);
        float mx = fmaxf(fmaxf(l0,l1), fmaxf(l2,l3));
        float p0=__expf(l0-mx), p1=__expf(l1-mx);
        float p2=__expf(l2-mx), p3=__expf(l3-mx);
        float inv = 1.f/(p0+p1+p2+p3);
        p0*=inv; p1*=inv; p2*=inv; p3*=inv;
        const float* eb = emb + he*8;
        f32x4 ya = ld4(eb)*p0      + ld4(eb+16)*p1 +
                   ld4(eb+32)*p2   + ld4(eb+48)*p3;
        f32x4 yb = ld4(eb+4)*p0    + ld4(eb+20)*p1 +
                   ld4(eb+36)*p2   + ld4(eb+52)*p3;
        yf = mk8v(ya, yb);
        if (hi >= 2) yf = zero8();
      }
    }
    if (hi == 0) *(f32x4*)(out + (size_t)col*4) = lgv;
  }
}

extern "C" void kernel_launch(void* const* d_in, const int* in_sizes, int n_in,
                              void* d_out, int out_size, void* d_ws, size_t ws_size,
                              hipStream_t stream) {
  const float* state = (const float*)d_in[0];
  const int*   pact  = (const int*)  d_in[1];
  const float* z0    = (const float*)d_in[2];
  const float* Wt1   = (const float*)d_in[3];
  const float* bt1   = (const float*)d_in[4];
  const float* Wt2   = (const float*)d_in[5];
  const float* bt2   = (const float*)d_in[6];
  const float* Wh1   = (const float*)d_in[7];
  const float* bh1   = (const float*)d_in[8];
  const float* Wh2   = (const float*)d_in[9];
  const float* bh2   = (const float*)d_in[10];
  const float* emb   = (const float*)d_in[11];
  float* out = (float*)d_out;

  const int B = in_sizes[0] / 64;         // 524288
  const int ntiles = B / 16;              // 32768
  const int blocks = 1024;                // 4 waves/block -> 4096 waves
  const int wstride = blocks * 4;
  trm_mfma<<<blocks, 256, 0, stream>>>(state, pact, z0, Wt1, bt1, Wt2, bt2,
                                       Wh1, bh1, Wh2, bh2, emb, out,
                                       ntiles, wstride);
}

// Round 4
// 69.495 us; speedup vs baseline: 12.3708x; 1.0528x over previous
//
#include <hip/hip_runtime.h>
#include <hip/hip_bf16.h>

typedef __attribute__((ext_vector_type(8))) short bf16x8;
typedef __attribute__((ext_vector_type(4))) float f32x4;

#define MFMA16(A,B,C) __builtin_amdgcn_mfma_f32_16x16x32_bf16((A),(B),(C),0,0,0)

static __device__ __forceinline__ f32x4 ld4(const float* p){
  return *(const f32x4*)p;
}
// Single-instruction packed f32->bf16 (RTNE). dst.lo = bf16(a), dst.hi = bf16(b).
static __device__ __forceinline__ unsigned pk2(float a, float b){
  unsigned r;
  asm("v_cvt_pk_bf16_f32 %0, %1, %2" : "=v"(r) : "v"(a), "v"(b));
  return r;
}
static __device__ __forceinline__ bf16x8 mk8(float a,float b,float c,float d,
                                             float e,float f,float g,float h){
  union { bf16x8 v; unsigned u[4]; } r;
  r.u[0]=pk2(a,b); r.u[1]=pk2(c,d); r.u[2]=pk2(e,f); r.u[3]=pk2(g,h);
  return r.v;
}
static __device__ __forceinline__ bf16x8 mk8v(f32x4 a, f32x4 b){
  return mk8(a[0],a[1],a[2],a[3],b[0],b[1],b[2],b[3]);
}
static __device__ __forceinline__ bf16x8 mk8r(f32x4 a, f32x4 b){ // relu + pack
  return mk8(fmaxf(a[0],0.f),fmaxf(a[1],0.f),fmaxf(a[2],0.f),fmaxf(a[3],0.f),
             fmaxf(b[0],0.f),fmaxf(b[1],0.f),fmaxf(b[2],0.f),fmaxf(b[3],0.f));
}
static __device__ __forceinline__ bf16x8 zero8(){
  bf16x8 v;
  #pragma unroll
  for(int i=0;i<8;++i) v[i]=0;
  return v;
}
// Pin: asm-touched values cannot be rematerialized by the register allocator,
// forcing true residency of persistent fragments (R3 post-mortem: VGPR=124
// proved LLVM was re-loading + re-packing all weights EVERY tile -> ~1050
// VALU instrs/tile vs ~240 static).
static __device__ __forceinline__ void keepv(bf16x8& v){ asm("" : "+v"(v)); }
static __device__ __forceinline__ void keepf(f32x4& v){ asm("" : "+v"(v)); }

// Layout conventions (verified C/D layout, learn_hip m89):
//   A-frag: row = lane&15, k = (lane>>4)*8 + j          (weights)
//   B-frag: col = lane&15, k = (lane>>4)*8 + j          (batch activations)
//   C/D   : col = lane&15, row = (lane>>4)*4 + reg
// Scramble sigma: feature h = Mt*16 + hi*4 + reg  <->  k-slot Kt*32 + hi*8 + jj
//   with Kt = Mt>>1, jj = (Mt&1)*4 + reg. Applied to Wt2/Wh2 K-cols, z-cols
//   of Wt1/Wh1, and z0, so layer-out -> layer-in needs no cross-lane moves.
__global__ __launch_bounds__(256, 1) void trm_mfma(
    const float* __restrict__ state, const int* __restrict__ pact,
    const float* __restrict__ z0,
    const float* __restrict__ Wt1, const float* __restrict__ bt1,
    const float* __restrict__ Wt2, const float* __restrict__ bt2,
    const float* __restrict__ Wh1, const float* __restrict__ bh1,
    const float* __restrict__ Wh2, const float* __restrict__ bh2,
    const float* __restrict__ emb, float* __restrict__ out,
    int ntiles, int wstride)
{
  const int lane = threadIdx.x & 63;
  const int wid  = blockIdx.x * (blockDim.x >> 6) + (threadIdx.x >> 6);
  const int r16  = lane & 15;   // A-row / B-col / C-col
  const int hi   = lane >> 4;   // k-group (inputs) / row-group (C)
  const int he   = hi & 1;      // clamped group for 16-wide (y) loads

  // ---------------- weight / bias / z0 fragments (persistent, pinned) ------
  bf16x8 wt1f[4][4];
  #pragma unroll
  for (int m=0;m<4;++m){
    const float* w = Wt1 + (m*16 + r16)*112;
    wt1f[m][0] = mk8v(ld4(w + hi*4),       ld4(w + 16 + hi*4));   // z (scrambled)
    wt1f[m][1] = mk8v(ld4(w + 32 + hi*8),  ld4(w + 36 + hi*8));   // x[0:32]
    wt1f[m][2] = mk8v(ld4(w + 64 + hi*8),  ld4(w + 68 + hi*8));   // x[32:64]
    bf16x8 yfrag = mk8v(ld4(w + 96 + he*8), ld4(w + 100 + he*8)); // y(16)+pad
    if (hi >= 2) yfrag = zero8();
    wt1f[m][3] = yfrag;
    keepv(wt1f[m][0]); keepv(wt1f[m][1]); keepv(wt1f[m][2]); keepv(wt1f[m][3]);
  }
  bf16x8 wt2f[2][2];
  #pragma unroll
  for (int m=0;m<2;++m){
    const float* w = Wt2 + (m*16 + r16)*64;
    wt2f[m][0] = mk8v(ld4(w + hi*4),      ld4(w + 16 + hi*4));    // h-cols scrambled
    wt2f[m][1] = mk8v(ld4(w + 32 + hi*4), ld4(w + 48 + hi*4));
    keepv(wt2f[m][0]); keepv(wt2f[m][1]);
  }
  bf16x8 wh1f[2][2];
  #pragma unroll
  for (int m=0;m<2;++m){
    const float* w = Wh1 + (m*16 + r16)*48;
    wh1f[m][0] = mk8v(ld4(w + hi*4), ld4(w + 16 + hi*4));         // z (scrambled)
    bf16x8 yfrag = mk8v(ld4(w + 32 + he*8), ld4(w + 36 + he*8));  // y(16)+pad
    if (hi >= 2) yfrag = zero8();
    wh1f[m][1] = yfrag;
    keepv(wh1f[m][0]); keepv(wh1f[m][1]);
  }
  bf16x8 wh2f;
  {
    const float* w = Wh2 + ((r16 < 4) ? r16 : 0)*32;
    bf16x8 t = mk8v(ld4(w + hi*4), ld4(w + 16 + hi*4));           // h-cols scrambled
    if (r16 >= 4) t = zero8();                                    // pad rows 4..15
    wh2f = t;
    keepv(wh2f);
  }
  f32x4 bt1r[4], bt2r[2], bh1r[2], bh2r;
  #pragma unroll
  for (int m=0;m<4;++m){ bt1r[m] = ld4(bt1 + m*16 + hi*4); keepf(bt1r[m]); }
  #pragma unroll
  for (int m=0;m<2;++m){ bt2r[m] = ld4(bt2 + m*16 + hi*4); keepf(bt2r[m]); }
  #pragma unroll
  for (int m=0;m<2;++m){ bh1r[m] = ld4(bh1 + m*16 + hi*4); keepf(bh1r[m]); }
  {
    f32x4 t = ld4(bh2);
    float msk = (hi == 0) ? 1.f : 0.f;
    bh2r = t * msk;
    keepf(bh2r);
  }
  bf16x8 z0f = mk8v(ld4(z0 + hi*4), ld4(z0 + 16 + hi*4));         // scrambled
  keepv(z0f);

  // ---------------- batch-tile loop (16 cols per wave-iteration) -----------
  // Register double-buffer for the per-tile global loads (state + action):
  // issue tile t+1's loads at the top of tile t's compute so the ~500cy
  // global latency hides under the MFMA chain.
  int t = wid;
  f32x4 cx0, cx1, cx2, cx3; int cact;
  {
    const int col = t*16 + r16;
    const float* xr = state + (size_t)col*64;
    cx0 = ld4(xr + hi*8);      cx1 = ld4(xr + hi*8 + 4);
    cx2 = ld4(xr + 32 + hi*8); cx3 = ld4(xr + 36 + hi*8);
    cact = pact[col];
  }

  #pragma unroll 1
  for (; t < ntiles; t += wstride){
    const int tn = t + wstride;
    f32x4 nx0, nx1, nx2, nx3; int nact = 0;
    if (tn < ntiles){
      const int coln = tn*16 + r16;
      const float* xrn = state + (size_t)coln*64;
      nx0 = ld4(xrn + hi*8);      nx1 = ld4(xrn + hi*8 + 4);
      nx2 = ld4(xrn + 32 + hi*8); nx3 = ld4(xrn + 36 + hi*8);
      nact = pact[coln];
    }

    const int col = t*16 + r16;
    bf16x8 xf0 = mk8v(cx0, cx1);
    bf16x8 xf1 = mk8v(cx2, cx3);
    bf16x8 yf;
    {
      const float* er = emb + cact*16 + he*8;
      yf = mk8v(ld4(er), ld4(er + 4));
      if (hi >= 2) yf = zero8();
    }
    bf16x8 zf = z0f;
    f32x4 lgv;

    #pragma unroll
    for (int s=0;s<2;++s){
      #pragma unroll
      for (int it=0; it<2; ++it){
        f32x4 c0=bt1r[0], c1=bt1r[1], c2=bt1r[2], c3=bt1r[3];
        c0=MFMA16(wt1f[0][0], zf,  c0); c1=MFMA16(wt1f[1][0], zf,  c1);
        c2=MFMA16(wt1f[2][0], zf,  c2); c3=MFMA16(wt1f[3][0], zf,  c3);
        c0=MFMA16(wt1f[0][1], xf0, c0); c1=MFMA16(wt1f[1][1], xf0, c1);
        c2=MFMA16(wt1f[2][1], xf0, c2); c3=MFMA16(wt1f[3][1], xf0, c3);
        c0=MFMA16(wt1f[0][2], xf1, c0); c1=MFMA16(wt1f[1][2], xf1, c1);
        c2=MFMA16(wt1f[2][2], xf1, c2); c3=MFMA16(wt1f[3][2], xf1, c3);
        c0=MFMA16(wt1f[0][3], yf,  c0); c1=MFMA16(wt1f[1][3], yf,  c1);
        c2=MFMA16(wt1f[2][3], yf,  c2); c3=MFMA16(wt1f[3][3], yf,  c3);
        bf16x8 h0 = mk8r(c0, c1);             // K-tile 0 of hidden (scrambled)
        bf16x8 h1 = mk8r(c2, c3);             // K-tile 1
        f32x4 d0 = bt2r[0], d1 = bt2r[1];
        d0=MFMA16(wt2f[0][0], h0, d0); d1=MFMA16(wt2f[1][0], h0, d1);
        d0=MFMA16(wt2f[0][1], h1, d0); d1=MFMA16(wt2f[1][1], h1, d1);
        zf = mk8v(d0, d1);                    // z (scrambled), in-lane
      }
      f32x4 g0 = bh1r[0], g1 = bh1r[1];
      g0=MFMA16(wh1f[0][0], zf, g0); g1=MFMA16(wh1f[1][0], zf, g1);
      g0=MFMA16(wh1f[0][1], yf, g0); g1=MFMA16(wh1f[1][1], yf, g1);
      bf16x8 hh = mk8r(g0, g1);
      f32x4 cl = bh2r;
      cl = MFMA16(wh2f, hh, cl);              // logits: hi==0 lanes, regs 0..3
      lgv = cl;
      if (s == 0){
        float l0 = __shfl(cl[0], r16), l1 = __shfl(cl[1], r16);
        float l2 = __shfl(cl[2], r16), l3 = __shfl(cl[3], r16);
        float mx = fmaxf(fmaxf(l0,l1), fmaxf(l2,l3));
        float p0=__expf(l0-mx), p1=__expf(l1-mx);
        float p2=__expf(l2-mx), p3=__expf(l3-mx);
        float inv = 1.f/(p0+p1+p2+p3);
        p0*=inv; p1*=inv; p2*=inv; p3*=inv;
        const float* eb = emb + he*8;
        f32x4 ya = ld4(eb)*p0      + ld4(eb+16)*p1 +
                   ld4(eb+32)*p2   + ld4(eb+48)*p3;
        f32x4 yb = ld4(eb+4)*p0    + ld4(eb+20)*p1 +
                   ld4(eb+36)*p2   + ld4(eb+52)*p3;
        yf = mk8v(ya, yb);
        if (hi >= 2) yf = zero8();
      }
    }
    if (hi == 0) *(f32x4*)(out + (size_t)col*4) = lgv;

    cx0 = nx0; cx1 = nx1; cx2 = nx2; cx3 = nx3; cact = nact;
  }
}

extern "C" void kernel_launch(void* const* d_in, const int* in_sizes, int n_in,
                              void* d_out, int out_size, void* d_ws, size_t ws_size,
                              hipStream_t stream) {
  const float* state = (const float*)d_in[0];
  const int*   pact  = (const int*)  d_in[1];
  const float* z0    = (const float*)d_in[2];
  const float* Wt1   = (const float*)d_in[3];
  const float* bt1   = (const float*)d_in[4];
  const float* Wt2   = (const float*)d_in[5];
  const float* bt2   = (const float*)d_in[6];
  const float* Wh1   = (const float*)d_in[7];
  const float* bh1   = (const float*)d_in[8];
  const float* Wh2   = (const float*)d_in[9];
  const float* bh2   = (const float*)d_in[10];
  const float* emb   = (const float*)d_in[11];
  float* out = (float*)d_out;

  const int B = in_sizes[0] / 64;         // 524288
  const int ntiles = B / 16;              // 32768
  const int blocks = 1024;                // 4 waves/block -> 4096 waves
  const int wstride = blocks * 4;
  trm_mfma<<<blocks, 256, 0, stream>>>(state, pact, z0, Wt1, bt1, Wt2, bt2,
                                       Wh1, bh1, Wh2, bh2, emb, out,
                                       ntiles, wstride);
}